// Round 1
// baseline (644.487 us; speedup 1.0000x reference)
//
#include <hip/hip_runtime.h>

#define FDIM 16

// ---------------------------------------------------------------------------
// Mip downsample: dst texel = mean of 2x2 src texels. One thread per
// (plane, y, x, feature-group-of-4) of the destination level.
// ---------------------------------------------------------------------------
__global__ void downsample_kernel(const float* __restrict__ src,
                                  float* __restrict__ dst, int dstS) {
    int t = blockIdx.x * blockDim.x + threadIdx.x;
    int total = 3 * dstS * dstS * 4;  // float4 groups
    if (t >= total) return;
    int g = t & 3;
    int rest = t >> 2;
    int x = rest % dstS;
    rest /= dstS;
    int y = rest % dstS;
    int plane = rest / dstS;
    int srcS = dstS * 2;

    const float4* s =
        (const float4*)(src + (size_t)plane * srcS * srcS * FDIM);
    // float4-unit index: texel (yy, xx) group g -> (yy*srcS + xx)*4 + g
    size_t r0 = ((size_t)(2 * y) * srcS + 2 * x) * 4 + g;
    size_t r1 = r0 + 4;                  // x+1
    size_t r2 = r0 + (size_t)srcS * 4;   // y+1
    size_t r3 = r2 + 4;
    float4 a = s[r0], b = s[r1], c = s[r2], d = s[r3];
    float4 o;
    o.x = (a.x + b.x + c.x + d.x) * 0.25f;
    o.y = (a.y + b.y + c.y + d.y) * 0.25f;
    o.z = (a.z + b.z + c.z + d.z) * 0.25f;
    o.w = (a.w + b.w + c.w + d.w) * 0.25f;

    float4* dp = (float4*)(dst + (size_t)plane * dstS * dstS * FDIM);
    dp[((size_t)y * dstS + x) * 4 + g] = o;
}

// Offset (in floats) of mip level l (1..7) within the mips workspace.
// off[l] = 48 * sum_{j=1}^{l-1} S_j^2, S_j = 512>>j  ->  closed form:
__device__ __forceinline__ size_t mip_offset(int l) {
    return (size_t)16u * (262144u - (1u << (20 - 2 * l)));
}

__device__ __forceinline__ const float4* level_plane_base(
    const float* __restrict__ fm, const float* __restrict__ mips, int l,
    int plane) {
    const float* base = (l == 0) ? fm : (mips + mip_offset(l));
    int S = 512 >> l;
    return (const float4*)(base + (size_t)plane * S * S * FDIM);
}

// Bilinear sample of feature-group g at (u,v) from an SxS texture.
// Matches reference: pos = uv*S - 0.5, floor, clamp indices, exact lerp form.
__device__ __forceinline__ float4 sample_bilinear(const float4* __restrict__ tex,
                                                  int S, float u, float v,
                                                  int g) {
    float posx = u * (float)S - 0.5f;
    float posy = v * (float)S - 0.5f;
    float fpx = floorf(posx);
    float fpy = floorf(posy);
    float fx = posx - fpx;
    float fy = posy - fpy;
    int ix0 = (int)fpx;
    int iy0 = (int)fpy;
    int ix1 = min(max(ix0 + 1, 0), S - 1);
    int iy1 = min(max(iy0 + 1, 0), S - 1);
    ix0 = min(max(ix0, 0), S - 1);
    iy0 = min(max(iy0, 0), S - 1);

    float4 v00 = tex[((size_t)iy0 * S + ix0) * 4 + g];
    float4 v10 = tex[((size_t)iy0 * S + ix1) * 4 + g];
    float4 v01 = tex[((size_t)iy1 * S + ix0) * 4 + g];
    float4 v11 = tex[((size_t)iy1 * S + ix1) * 4 + g];

    float gx = 1.0f - fx, gy = 1.0f - fy;
    float4 r;
    r.x = (v00.x * gx + v10.x * fx) * gy + (v01.x * gx + v11.x * fx) * fy;
    r.y = (v00.y * gx + v10.y * fx) * gy + (v01.y * gx + v11.y * fx) * fy;
    r.z = (v00.z * gx + v10.z * fx) * gy + (v01.z * gx + v11.z * fx) * fy;
    r.w = (v00.w * gx + v10.w * fx) * gy + (v01.w * gx + v11.w * fx) * fy;
    return r;
}

// ---------------------------------------------------------------------------
// Main kernel: thread t -> (point p, plane, feature-group g).
// t = ((p*3 + plane) << 2) | g, so a 64-lane wave covers 16 consecutive
// samples: each texel gather is one 64B segment across a lane-quad, and the
// wave's output stores form 1 KiB of contiguous float4 writes.
// ---------------------------------------------------------------------------
__global__ void trimip_kernel(const float* __restrict__ x,
                              const float* __restrict__ level,
                              const float* __restrict__ fm,
                              const float* __restrict__ mips,
                              float* __restrict__ out, int n) {
    int t = blockIdx.x * blockDim.x + threadIdx.x;
    if (t >= n * 12) return;
    int g = t & 3;
    int s = t >> 2;        // sample = p*3 + plane
    int plane = s % 3;
    int p = s / 3;

    float lvl = level[p];
    lvl = fminf(fmaxf(lvl, 0.0f), 7.0f);
    int l0 = (int)floorf(lvl);
    if (l0 > 7) l0 = 7;
    int l1 = min(l0 + 1, 7);
    float fr = lvl - (float)l0;

    float x0 = x[3 * p + 0];
    float x1 = x[3 * p + 1];
    float x2 = x[3 * p + 2];
    // uv[...,0] = column (x index), uv[...,1] = row (y index); gather t[row,col]
    float u, v;
    if (plane == 0) { u = x1; v = x2; }
    else if (plane == 1) { u = x0; v = x2; }
    else { u = x0; v = x1; }

    int S0 = 512 >> l0;
    const float4* t0 = level_plane_base(fm, mips, l0, plane);
    float4 a = sample_bilinear(t0, S0, u, v, g);

    int S1 = 512 >> l1;
    const float4* t1 = level_plane_base(fm, mips, l1, plane);
    float4 b = sample_bilinear(t1, S1, u, v, g);

    float w0 = 1.0f - fr;
    float4 r;
    r.x = a.x * w0 + b.x * fr;
    r.y = a.y * w0 + b.y * fr;
    r.z = a.z * w0 + b.z * fr;
    r.w = a.w * w0 + b.w * fr;

    // out[p, plane*16 + g*4 .. +4)
    ((float4*)out)[(size_t)p * 12 + plane * 4 + g] = r;
}

extern "C" void kernel_launch(void* const* d_in, const int* in_sizes, int n_in,
                              void* d_out, int out_size, void* d_ws,
                              size_t ws_size, hipStream_t stream) {
    const float* x = (const float*)d_in[0];
    const float* level = (const float*)d_in[1];
    const float* fm = (const float*)d_in[2];
    float* out = (float*)d_out;
    float* ws = (float*)d_ws;  // mips live here: levels 1..7, 16.8 MB total

    int n = in_sizes[0] / 3;

    // Build the mip pyramid (ws is re-poisoned before every call).
    // Host-side copy of mip_offset():
    size_t off[8];
    off[0] = 0;
    for (int l = 1; l <= 7; ++l)
        off[l] = (size_t)16u * (262144u - (1u << (20 - 2 * l)));

    for (int l = 1; l <= 7; ++l) {
        int dstS = 512 >> l;
        const float* src = (l == 1) ? fm : (ws + off[l - 1]);
        float* dst = ws + off[l];
        int total = 3 * dstS * dstS * 4;
        int blocks = (total + 255) / 256;
        downsample_kernel<<<blocks, 256, 0, stream>>>(src, dst, dstS);
    }

    long long threads = (long long)n * 12;
    int blocks = (int)((threads + 255) / 256);
    trimip_kernel<<<blocks, 256, 0, stream>>>(x, level, fm, ws, out, n);
}